// Round 1
// baseline (303.226 us; speedup 1.0000x reference)
//
#include <hip/hip_runtime.h>
#include <math.h>

// x[32,4096,32] f32, codebook[256,32] f32
// outputs (concat f32): o_idx[N], o_probs[N*256], o_quants[N*32], o_loss[N]
constexpr int D    = 32;
constexpr int K    = 256;
constexpr int ROWS = 64;   // rows per block (= lanes per wave)
constexpr int WPB  = 8;    // waves per block (512 threads)
constexpr int CPT  = 32;   // codes per thread (K / WPB)

__global__ __launch_bounds__(512, 4) void vq_kernel(
    const float* __restrict__ x,
    const float* __restrict__ cb,
    float* __restrict__ o_idx,
    float* __restrict__ o_probs,
    float* __restrict__ o_quants,
    float* __restrict__ o_loss)
{
    // Union region: phase 1 = code norms cnl[256] (1 KB, at base); phase 2 =
    // transpose buffer pbuf[8][64][5] float4 (40 KB). Last cnl read happens
    // before the mred barrier; first pbuf write happens after the sred
    // barrier -> >=1 barrier separates the two uses.
    // NOTE: the codebook itself is NOT staged in LDS anymore. The distance
    // loop's 256 reads/thread are wave-uniform broadcasts; on the LDS pipe
    // they serialize at ~12 cyc/ds_read_b128 (the kernel's bottleneck).
    // Reading the 32 KB codebook directly from global gives single-request
    // L1-hit broadcasts on the otherwise idle VMEM pipe instead.
    __shared__ __align__(16) char smem_u[40960];
    __shared__ float mred[WPB][ROWS];
    __shared__ float sred[WPB][ROWS];
    __shared__ int   ired[WPB][ROWS];

    float*  cnl  = reinterpret_cast<float*>(smem_u);            // [K]
    float4* pbuf = reinterpret_cast<float4*>(smem_u);           // [8][64][5]

    const int tid = threadIdx.x;
    const int l   = tid & 63;          // lane = local row
    const int w   = tid >> 6;          // wave id (wave-uniform)
    const int row = blockIdx.x * ROWS + l;

    // --- per-code squared norm: 2 threads per code, pair-combine via shuffle ---
    {
        const int c = tid >> 1, h = tid & 1;
        const float4* p = reinterpret_cast<const float4*>(cb) + c * (D / 4) + h * 4;
        float a = 0.f;
        #pragma unroll
        for (int i = 0; i < 4; ++i) {
            float4 v = p[i];
            a += v.x * v.x + v.y * v.y + v.z * v.z + v.w * v.w;
        }
        a += __shfl_xor(a, 1);
        if (h == 0) cnl[c] = a;
    }

    // --- x row into registers ---
    float xr[D];
    {
        const float4* xv = reinterpret_cast<const float4*>(x) + (size_t)row * (D / 4);
        #pragma unroll
        for (int i = 0; i < D / 4; ++i) {
            float4 v = xv[i];
            xr[4 * i + 0] = v.x; xr[4 * i + 1] = v.y;
            xr[4 * i + 2] = v.z; xr[4 * i + 3] = v.w;
        }
    }
    float xx;
    {
        float a0 = 0.f, a1 = 0.f, a2 = 0.f, a3 = 0.f;
        #pragma unroll
        for (int j = 0; j < D; j += 4) {
            a0 += xr[j] * xr[j];         a1 += xr[j + 1] * xr[j + 1];
            a2 += xr[j + 2] * xr[j + 2]; a3 += xr[j + 3] * xr[j + 3];
        }
        xx = (a0 + a1) + (a2 + a3);
    }
    __syncthreads();   // cnl ready

    // --- distance pass: wave w covers codes [32w, 32w+32) ---
    // Codebook read DIRECTLY from global: 64 lanes present the same address,
    // the TA merges them into one L1-hit request per instruction (codebook is
    // 32 KB = L1-resident). This keeps the hot loop off the LDS pipe; every
    // MAC is an all-VGPR v_fma_f32 as before.
    const int kbase = w * CPT;
    const float4* cw = reinterpret_cast<const float4*>(cb) + kbase * (D / 4);
    float lg[CPT];
    #pragma unroll
    for (int j = 0; j < CPT; ++j) {
        float d0 = 0.f, d1 = 0.f, d2 = 0.f, d3 = 0.f;
        #pragma unroll
        for (int t = 0; t < D / 4; ++t) {
            float4 c4 = cw[j * (D / 4) + t];
            d0 += xr[4 * t + 0] * c4.x; d1 += xr[4 * t + 1] * c4.y;
            d2 += xr[4 * t + 2] * c4.z; d3 += xr[4 * t + 3] * c4.w;
        }
        float dot = (d0 + d1) + (d2 + d3);
        lg[j] = 2.0f * dot - (xx + cnl[kbase + j]);   // = -d2
    }

    // --- local first-max argmax (strict > keeps lowest j) ---
    float m = lg[0]; int bi = 0;
    #pragma unroll
    for (int j = 1; j < CPT; ++j) {
        bool gt = lg[j] > m;
        m  = gt ? lg[j] : m;
        bi = gt ? j : bi;
    }
    mred[w][l] = m;
    ired[w][l] = kbase + bi;
    __syncthreads();   // also: last reads of cnl are done

    // --- cross-wave combine, ascending wave order keeps first occurrence ---
    float gm = mred[0][l]; int gi = ired[0][l];
    #pragma unroll
    for (int ww = 1; ww < WPB; ++ww) {
        float mw = mred[ww][l];
        bool gt  = mw > gm;
        gi = gt ? ired[ww][l] : gi;
        gm = gt ? mw : gm;
    }

    // --- exp in place + local sum ---
    float s = 0.f;
    #pragma unroll
    for (int j = 0; j < CPT; ++j) {
        float e = __expf(lg[j] - gm);
        lg[j] = e;
        s += e;
    }
    sred[w][l] = s;
    __syncthreads();   // after this barrier the union region may become pbuf

    float gs = 0.f;
    #pragma unroll
    for (int ww = 0; ww < WPB; ++ww) gs += sred[ww][l];
    const float rs = 1.0f / gs;

    // --- side outputs (wave-uniform branch) ---
    if (w == 4) {
        o_idx[row] = (float)gi;
    } else if (w == 5) {
        // loss = 1.25 * d2min / 32, and d2min = -gm  (free!)
        o_loss[row] = gm * (-1.25f / (float)D);
    } else if (w >= 6) {
        // quants = codebook[gi]; two waves split the 8 float4 (global cb, L1/L2-hot)
        const int half = w - 6;   // 0 or 1
        const float4* cg = reinterpret_cast<const float4*>(cb) + gi * (D / 4) + half * 4;
        float4* qv = reinterpret_cast<float4*>(o_quants) + (size_t)row * (D / 4) + half * 4;
        #pragma unroll
        for (int i = 0; i < 4; ++i) qv[i] = cg[i];
    }

    // --- probs: per-wave private LDS transpose (same-wave DS ops are in-order),
    //     16-code halves, stores are 64B-contiguous segments ---
    float4* op = reinterpret_cast<float4*>(o_probs);
    const int rowbase = blockIdx.x * ROWS;
    #pragma unroll
    for (int h = 0; h < 2; ++h) {
        float4* pb = pbuf + ((size_t)w * ROWS + l) * 5;
        #pragma unroll
        for (int i = 0; i < 4; ++i) {
            int j = h * 16 + i * 4;
            pb[i] = make_float4(lg[j] * rs, lg[j + 1] * rs,
                                lg[j + 2] * rs, lg[j + 3] * rs);
        }
        #pragma unroll
        for (int i = 0; i < 4; ++i) {
            int e  = i * 64 + l;
            int r  = e >> 2;      // 4 float4 (16 codes) per row
            int c4 = e & 3;
            float4 v = pbuf[((size_t)w * ROWS + r) * 5 + c4];
            op[(size_t)(rowbase + r) * (K / 4) + w * 8 + h * 4 + c4] = v;
        }
    }
}

extern "C" void kernel_launch(void* const* d_in, const int* in_sizes, int n_in,
                              void* d_out, int out_size, void* d_ws, size_t ws_size,
                              hipStream_t stream) {
    const float* x  = (const float*)d_in[0];
    const float* cb = (const float*)d_in[1];
    const int N = in_sizes[0] / D;   // 131072

    float* out      = (float*)d_out;
    float* o_idx    = out;
    float* o_probs  = o_idx + N;
    float* o_quants = o_probs + (size_t)N * K;
    float* o_loss   = o_quants + (size_t)N * D;

    const int grid = N / ROWS;   // 2048 blocks of 512 threads
    vq_kernel<<<grid, 512, 0, stream>>>(x, cb, o_idx, o_probs, o_quants, o_loss);
}

// Round 2
// 256.979 us; speedup vs baseline: 1.1800x; 1.1800x over previous
//
#include <hip/hip_runtime.h>
#include <math.h>

// x[32,4096,32] f32, codebook[256,32] f32
// outputs (concat f32): o_idx[N], o_probs[N*256], o_quants[N*32], o_loss[N]
constexpr int D    = 32;
constexpr int K    = 256;
constexpr int ROWS = 64;   // rows per block (= lanes per wave)
constexpr int WPB  = 8;    // waves per block (512 threads)
constexpr int CPT  = 32;   // codes per thread (K / WPB)

typedef __attribute__((ext_vector_type(16))) float f32x16;

__global__ __launch_bounds__(512, 4) void vq_kernel(
    const float* __restrict__ x,
    const float* __restrict__ cb,
    float* __restrict__ o_idx,
    float* __restrict__ o_probs,
    float* __restrict__ o_quants,
    float* __restrict__ o_loss)
{
    // Union region: phase 1 = code norms cnl[256] (1 KB, at base); phase 2 =
    // transpose buffer pbuf[8][64][5] float4 (40 KB). Last cnl read happens
    // before the mred barrier; first pbuf write happens after the sred
    // barrier -> >=1 barrier separates the two uses.
    //
    // Codebook path history:
    //   LDS broadcast  (r0): 256 ds_read_b128/thread @ ~12cyc -> ~80 us kernel
    //   global broadcast(r1): same count on VMEM pipe          -> 187 us kernel
    //   s_load -> SGPR (r2): wave-uniform data on the IDLE scalar pipe; the
    //   hot loop issues zero LDS/VMEM ops, every MAC is v_fma_f32 v,s,v,v.
    __shared__ __align__(16) char smem_u[40960];
    __shared__ float mred[WPB][ROWS];
    __shared__ float sred[WPB][ROWS];
    __shared__ int   ired[WPB][ROWS];

    float*  cnl  = reinterpret_cast<float*>(smem_u);            // [K]
    float4* pbuf = reinterpret_cast<float4*>(smem_u);           // [8][64][5]

    const int tid = threadIdx.x;
    const int l   = tid & 63;          // lane = local row
    const int w   = tid >> 6;          // wave id (wave-uniform)
    const int row = blockIdx.x * ROWS + l;

    // --- per-code squared norm: 2 threads per code, pair-combine via shuffle ---
    {
        const int c = tid >> 1, h = tid & 1;
        const float4* p = reinterpret_cast<const float4*>(cb) + c * (D / 4) + h * 4;
        float a = 0.f;
        #pragma unroll
        for (int i = 0; i < 4; ++i) {
            float4 v = p[i];
            a += v.x * v.x + v.y * v.y + v.z * v.z + v.w * v.w;
        }
        a += __shfl_xor(a, 1);
        if (h == 0) cnl[c] = a;
    }

    // --- x row into registers ---
    float xr[D];
    {
        const float4* xv = reinterpret_cast<const float4*>(x) + (size_t)row * (D / 4);
        #pragma unroll
        for (int i = 0; i < D / 4; ++i) {
            float4 v = xv[i];
            xr[4 * i + 0] = v.x; xr[4 * i + 1] = v.y;
            xr[4 * i + 2] = v.z; xr[4 * i + 3] = v.w;
        }
    }
    float xx;
    {
        float a0 = 0.f, a1 = 0.f, a2 = 0.f, a3 = 0.f;
        #pragma unroll
        for (int j = 0; j < D; j += 4) {
            a0 += xr[j] * xr[j];         a1 += xr[j + 1] * xr[j + 1];
            a2 += xr[j + 2] * xr[j + 2]; a3 += xr[j + 3] * xr[j + 3];
        }
        xx = (a0 + a1) + (a2 + a3);
    }
    __syncthreads();   // cnl ready

    // --- distance pass: wave w covers codes [32w, 32w+32) ---
    // The codebook slice is wave-uniform -> stream it through SGPRs with
    // s_load_dwordx16 on the scalar pipe. w is uniform across the wave but
    // the compiler can't prove it (tid>>6), so force uniformity with
    // readfirstlane and force the scalar load with inline asm. The
    // s_waitcnt lgkmcnt(0) is INSIDE the asm (SMEM returns out-of-order;
    // counted lgkmcnt is unsafe) and consumers depend on the =&s outputs,
    // so the data dependency is explicit.
    const int kbase = __builtin_amdgcn_readfirstlane(w) * CPT;
    const float* cwp = cb + (size_t)kbase * D;   // uniform base for this wave
    float lg[CPT];
    #pragma unroll
    for (int j = 0; j < CPT; ++j) {
        f32x16 c0, c1;
        asm volatile(
            "s_load_dwordx16 %0, %2, %3\n\t"
            "s_load_dwordx16 %1, %2, %4\n\t"
            "s_waitcnt lgkmcnt(0)"
            : "=&s"(c0), "=&s"(c1)
            : "s"(cwp), "i"(j * 128), "i"(j * 128 + 64));

        float d0 = 0.f, d1 = 0.f, d2 = 0.f, d3 = 0.f;
        #pragma unroll
        for (int t = 0; t < 4; ++t) {
            d0 += c0[4 * t + 0] * xr[4 * t + 0];
            d1 += c0[4 * t + 1] * xr[4 * t + 1];
            d2 += c0[4 * t + 2] * xr[4 * t + 2];
            d3 += c0[4 * t + 3] * xr[4 * t + 3];
        }
        #pragma unroll
        for (int t = 0; t < 4; ++t) {
            d0 += c1[4 * t + 0] * xr[16 + 4 * t + 0];
            d1 += c1[4 * t + 1] * xr[16 + 4 * t + 1];
            d2 += c1[4 * t + 2] * xr[16 + 4 * t + 2];
            d3 += c1[4 * t + 3] * xr[16 + 4 * t + 3];
        }
        float dot = (d0 + d1) + (d2 + d3);
        lg[j] = 2.0f * dot - (xx + cnl[kbase + j]);   // = -d2
    }

    // --- local first-max argmax (strict > keeps lowest j) ---
    float m = lg[0]; int bi = 0;
    #pragma unroll
    for (int j = 1; j < CPT; ++j) {
        bool gt = lg[j] > m;
        m  = gt ? lg[j] : m;
        bi = gt ? j : bi;
    }
    mred[w][l] = m;
    ired[w][l] = kbase + bi;
    __syncthreads();   // also: last reads of cnl are done

    // --- cross-wave combine, ascending wave order keeps first occurrence ---
    float gm = mred[0][l]; int gi = ired[0][l];
    #pragma unroll
    for (int ww = 1; ww < WPB; ++ww) {
        float mw = mred[ww][l];
        bool gt  = mw > gm;
        gi = gt ? ired[ww][l] : gi;
        gm = gt ? mw : gm;
    }

    // --- exp in place + local sum ---
    float s = 0.f;
    #pragma unroll
    for (int j = 0; j < CPT; ++j) {
        float e = __expf(lg[j] - gm);
        lg[j] = e;
        s += e;
    }
    sred[w][l] = s;
    __syncthreads();   // after this barrier the union region may become pbuf

    float gs = 0.f;
    #pragma unroll
    for (int ww = 0; ww < WPB; ++ww) gs += sred[ww][l];
    const float rs = 1.0f / gs;

    // --- side outputs (wave-uniform branch) ---
    if (w == 4) {
        o_idx[row] = (float)gi;
    } else if (w == 5) {
        // loss = 1.25 * d2min / 32, and d2min = -gm  (free!)
        o_loss[row] = gm * (-1.25f / (float)D);
    } else if (w >= 6) {
        // quants = codebook[gi]; two waves split the 8 float4 (global cb, L1/L2-hot)
        const int half = w - 6;   // 0 or 1
        const float4* cg = reinterpret_cast<const float4*>(cb) + gi * (D / 4) + half * 4;
        float4* qv = reinterpret_cast<float4*>(o_quants) + (size_t)row * (D / 4) + half * 4;
        #pragma unroll
        for (int i = 0; i < 4; ++i) qv[i] = cg[i];
    }

    // --- probs: per-wave private LDS transpose (same-wave DS ops are in-order),
    //     16-code halves, stores are 64B-contiguous segments ---
    float4* op = reinterpret_cast<float4*>(o_probs);
    const int rowbase = blockIdx.x * ROWS;
    #pragma unroll
    for (int h = 0; h < 2; ++h) {
        float4* pb = pbuf + ((size_t)w * ROWS + l) * 5;
        #pragma unroll
        for (int i = 0; i < 4; ++i) {
            int j = h * 16 + i * 4;
            pb[i] = make_float4(lg[j] * rs, lg[j + 1] * rs,
                                lg[j + 2] * rs, lg[j + 3] * rs);
        }
        #pragma unroll
        for (int i = 0; i < 4; ++i) {
            int e  = i * 64 + l;
            int r  = e >> 2;      // 4 float4 (16 codes) per row
            int c4 = e & 3;
            float4 v = pbuf[((size_t)w * ROWS + r) * 5 + c4];
            op[(size_t)(rowbase + r) * (K / 4) + w * 8 + h * 4 + c4] = v;
        }
    }
}

extern "C" void kernel_launch(void* const* d_in, const int* in_sizes, int n_in,
                              void* d_out, int out_size, void* d_ws, size_t ws_size,
                              hipStream_t stream) {
    const float* x  = (const float*)d_in[0];
    const float* cb = (const float*)d_in[1];
    const int N = in_sizes[0] / D;   // 131072

    float* out      = (float*)d_out;
    float* o_idx    = out;
    float* o_probs  = o_idx + N;
    float* o_quants = o_probs + (size_t)N * K;
    float* o_loss   = o_quants + (size_t)N * D;

    const int grid = N / ROWS;   // 2048 blocks of 512 threads
    vq_kernel<<<grid, 512, 0, stream>>>(x, cb, o_idx, o_probs, o_quants, o_loss);
}

// Round 3
// 209.260 us; speedup vs baseline: 1.4490x; 1.2280x over previous
//
#include <hip/hip_runtime.h>
#include <math.h>

// x[32,4096,32] f32, codebook[256,32] f32
// outputs (concat f32): o_idx[N], o_probs[N*256], o_quants[N*32], o_loss[N]
constexpr int D    = 32;
constexpr int K    = 256;
constexpr int LPW  = 64;    // lanes per wave
constexpr int WPB  = 8;     // waves per block (512 threads)
constexpr int CPT  = 32;    // codes per wave (K / WPB)
constexpr int RPT  = 2;     // rows per thread  <-- NEW: amortizes LDS broadcast
constexpr int ROWS = LPW * RPT;   // 128 rows per block

__global__ __launch_bounds__(512, 2) void vq_kernel(
    const float* __restrict__ x,
    const float* __restrict__ cb,
    float* __restrict__ o_idx,
    float* __restrict__ o_probs,
    float* __restrict__ o_quants,
    float* __restrict__ o_loss)
{
    // Union region: phase 1 = codebook cbl (32 KB) + norms cnl (1 KB);
    // phase 2 = transpose buffer pbuf[8][64][5] float4 (40 KB).
    // Last cbl/cnl read precedes the mred barrier; first pbuf write follows
    // the sred barrier -> >=1 barrier separates the phases.
    //
    // Cost model (r0-r2 ladder): the hot loop is LDS *return-bandwidth*
    // bound: each wave-uniform ds_read_b128 costs ~12cyc (1024B writeback)
    // whether broadcast or not. r0 (1 row/thread): 256 reads/wave, 2048
    // blocks -> ~82us of LDS pipe per CU. This version feeds each read to
    // TWO rows (8 FMA/lane per read), halving block count -> ~41us LDS.
    __shared__ __align__(16) char smem_u[40960];
    __shared__ float mred[WPB][RPT][LPW];
    __shared__ float sred[WPB][RPT][LPW];
    __shared__ int   ired[WPB][RPT][LPW];

    float*  cbl  = reinterpret_cast<float*>(smem_u);            // [K*D]
    float*  cnl  = reinterpret_cast<float*>(smem_u + 32768);    // [K]
    float4* pbuf = reinterpret_cast<float4*>(smem_u);           // [8][64][5]

    const int tid = threadIdx.x;
    const int l   = tid & 63;          // lane
    const int w   = tid >> 6;          // wave id (wave-uniform)
    const int row0 = blockIdx.x * ROWS + l;        // set 0
    const int row1 = row0 + LPW;                   // set 1

    // --- stage codebook into LDS (coalesced, 2048 float4) ---
    {
        const float4* cg = reinterpret_cast<const float4*>(cb);
        float4*       cl = reinterpret_cast<float4*>(cbl);
        #pragma unroll
        for (int i = 0; i < 4; ++i) cl[tid + i * 512] = cg[tid + i * 512];
    }
    // --- per-code squared norm: 2 threads per code, pair-combine via shuffle ---
    {
        const int c = tid >> 1, h = tid & 1;
        const float4* p = reinterpret_cast<const float4*>(cb) + c * (D / 4) + h * 4;
        float a = 0.f;
        #pragma unroll
        for (int i = 0; i < 4; ++i) {
            float4 v = p[i];
            a += v.x * v.x + v.y * v.y + v.z * v.z + v.w * v.w;
        }
        a += __shfl_xor(a, 1);
        if (h == 0) cnl[c] = a;
    }

    // --- both x rows into registers ---
    float xr0[D], xr1[D];
    {
        const float4* xv0 = reinterpret_cast<const float4*>(x) + (size_t)row0 * (D / 4);
        const float4* xv1 = reinterpret_cast<const float4*>(x) + (size_t)row1 * (D / 4);
        #pragma unroll
        for (int i = 0; i < D / 4; ++i) {
            float4 v = xv0[i];
            xr0[4 * i + 0] = v.x; xr0[4 * i + 1] = v.y;
            xr0[4 * i + 2] = v.z; xr0[4 * i + 3] = v.w;
        }
        #pragma unroll
        for (int i = 0; i < D / 4; ++i) {
            float4 v = xv1[i];
            xr1[4 * i + 0] = v.x; xr1[4 * i + 1] = v.y;
            xr1[4 * i + 2] = v.z; xr1[4 * i + 3] = v.w;
        }
    }
    float xx0, xx1;
    {
        float a0 = 0.f, a1 = 0.f, a2 = 0.f, a3 = 0.f;
        #pragma unroll
        for (int j = 0; j < D; j += 4) {
            a0 += xr0[j] * xr0[j];         a1 += xr0[j + 1] * xr0[j + 1];
            a2 += xr0[j + 2] * xr0[j + 2]; a3 += xr0[j + 3] * xr0[j + 3];
        }
        xx0 = (a0 + a1) + (a2 + a3);
        a0 = a1 = a2 = a3 = 0.f;
        #pragma unroll
        for (int j = 0; j < D; j += 4) {
            a0 += xr1[j] * xr1[j];         a1 += xr1[j + 1] * xr1[j + 1];
            a2 += xr1[j + 2] * xr1[j + 2]; a3 += xr1[j + 3] * xr1[j + 3];
        }
        xx1 = (a0 + a1) + (a2 + a3);
    }
    __syncthreads();   // cbl, cnl ready

    // --- distance pass: wave w covers codes [32w, 32w+32), both row sets ---
    // One wave-uniform broadcast read feeds 8 all-VGPR v_fma_f32 per lane.
    const int kbase = w * CPT;
    const float4* cwl = reinterpret_cast<const float4*>(cbl) + kbase * (D / 4);
    float lg0[CPT], lg1[CPT];
    #pragma unroll
    for (int j = 0; j < CPT; ++j) {
        float a0 = 0.f, a1 = 0.f, a2 = 0.f, a3 = 0.f;
        float b0 = 0.f, b1 = 0.f, b2 = 0.f, b3 = 0.f;
        #pragma unroll
        for (int t = 0; t < D / 4; ++t) {
            float4 c4 = cwl[j * (D / 4) + t];
            a0 += xr0[4 * t + 0] * c4.x; a1 += xr0[4 * t + 1] * c4.y;
            a2 += xr0[4 * t + 2] * c4.z; a3 += xr0[4 * t + 3] * c4.w;
            b0 += xr1[4 * t + 0] * c4.x; b1 += xr1[4 * t + 1] * c4.y;
            b2 += xr1[4 * t + 2] * c4.z; b3 += xr1[4 * t + 3] * c4.w;
        }
        const float cn = cnl[kbase + j];
        lg0[j] = 2.0f * ((a0 + a1) + (a2 + a3)) - (xx0 + cn);   // = -d2
        lg1[j] = 2.0f * ((b0 + b1) + (b2 + b3)) - (xx1 + cn);
    }

    // --- local first-max argmax (strict > keeps lowest j), both sets ---
    {
        float m = lg0[0]; int bi = 0;
        #pragma unroll
        for (int j = 1; j < CPT; ++j) {
            bool gt = lg0[j] > m;
            m  = gt ? lg0[j] : m;
            bi = gt ? j : bi;
        }
        mred[w][0][l] = m;
        ired[w][0][l] = kbase + bi;
    }
    {
        float m = lg1[0]; int bi = 0;
        #pragma unroll
        for (int j = 1; j < CPT; ++j) {
            bool gt = lg1[j] > m;
            m  = gt ? lg1[j] : m;
            bi = gt ? j : bi;
        }
        mred[w][1][l] = m;
        ired[w][1][l] = kbase + bi;
    }
    __syncthreads();   // also: last reads of cbl/cnl are done

    // --- cross-wave combine, ascending wave order keeps first occurrence ---
    float gm0 = mred[0][0][l]; int gi0 = ired[0][0][l];
    float gm1 = mred[0][1][l]; int gi1 = ired[0][1][l];
    #pragma unroll
    for (int ww = 1; ww < WPB; ++ww) {
        float mw0 = mred[ww][0][l];
        bool gt0  = mw0 > gm0;
        gi0 = gt0 ? ired[ww][0][l] : gi0;
        gm0 = gt0 ? mw0 : gm0;
        float mw1 = mred[ww][1][l];
        bool gt1  = mw1 > gm1;
        gi1 = gt1 ? ired[ww][1][l] : gi1;
        gm1 = gt1 ? mw1 : gm1;
    }

    // --- exp in place + local sums ---
    {
        float s0 = 0.f, s1 = 0.f;
        #pragma unroll
        for (int j = 0; j < CPT; ++j) {
            float e0 = __expf(lg0[j] - gm0);
            float e1 = __expf(lg1[j] - gm1);
            lg0[j] = e0; lg1[j] = e1;
            s0 += e0; s1 += e1;
        }
        sred[w][0][l] = s0;
        sred[w][1][l] = s1;
    }
    __syncthreads();   // after this barrier the union region may become pbuf

    float gs0 = 0.f, gs1 = 0.f;
    #pragma unroll
    for (int ww = 0; ww < WPB; ++ww) {
        gs0 += sred[ww][0][l];
        gs1 += sred[ww][1][l];
    }
    const float rs0 = 1.0f / gs0;
    const float rs1 = 1.0f / gs1;

    // --- side outputs (wave-uniform branch) ---
    if (w == 4) {
        o_idx[row0] = (float)gi0;
        o_idx[row1] = (float)gi1;
    } else if (w == 5) {
        // loss = 1.25 * d2min / 32, and d2min = -gm  (free!)
        o_loss[row0] = gm0 * (-1.25f / (float)D);
        o_loss[row1] = gm1 * (-1.25f / (float)D);
    } else if (w == 6) {
        // quants row-set 0: codebook[gi0] (global cb, L1/L2-hot)
        const float4* cg = reinterpret_cast<const float4*>(cb) + gi0 * (D / 4);
        float4* qv = reinterpret_cast<float4*>(o_quants) + (size_t)row0 * (D / 4);
        #pragma unroll
        for (int i = 0; i < D / 4; ++i) qv[i] = cg[i];
    } else if (w == 7) {
        // quants row-set 1
        const float4* cg = reinterpret_cast<const float4*>(cb) + gi1 * (D / 4);
        float4* qv = reinterpret_cast<float4*>(o_quants) + (size_t)row1 * (D / 4);
        #pragma unroll
        for (int i = 0; i < D / 4; ++i) qv[i] = cg[i];
    }

    // --- probs: per-wave private LDS transpose (same-wave DS ops are in-order),
    //     16-code halves, stores are 64B-contiguous segments. Two row sets
    //     reuse the same pbuf slot sequentially (same-wave ordering). ---
    float4* op = reinterpret_cast<float4*>(o_probs);
    auto emit_probs = [&](const float (&lgv)[CPT], float rsv, int rowbase) {
        #pragma unroll
        for (int h = 0; h < 2; ++h) {
            float4* pb = pbuf + ((size_t)w * LPW + l) * 5;
            #pragma unroll
            for (int i = 0; i < 4; ++i) {
                int j = h * 16 + i * 4;
                pb[i] = make_float4(lgv[j] * rsv, lgv[j + 1] * rsv,
                                    lgv[j + 2] * rsv, lgv[j + 3] * rsv);
            }
            #pragma unroll
            for (int i = 0; i < 4; ++i) {
                int e  = i * 64 + l;
                int r  = e >> 2;      // 4 float4 (16 codes) per row
                int c4 = e & 3;
                float4 v = pbuf[((size_t)w * LPW + r) * 5 + c4];
                op[(size_t)(rowbase + r) * (K / 4) + w * 8 + h * 4 + c4] = v;
            }
        }
    };
    emit_probs(lg0, rs0, blockIdx.x * ROWS);
    emit_probs(lg1, rs1, blockIdx.x * ROWS + LPW);
}

extern "C" void kernel_launch(void* const* d_in, const int* in_sizes, int n_in,
                              void* d_out, int out_size, void* d_ws, size_t ws_size,
                              hipStream_t stream) {
    const float* x  = (const float*)d_in[0];
    const float* cb = (const float*)d_in[1];
    const int N = in_sizes[0] / D;   // 131072

    float* out      = (float*)d_out;
    float* o_idx    = out;
    float* o_probs  = o_idx + N;
    float* o_quants = o_probs + (size_t)N * K;
    float* o_loss   = o_quants + (size_t)N * D;

    const int grid = N / ROWS;   // 1024 blocks of 512 threads
    vq_kernel<<<grid, 512, 0, stream>>>(x, cb, o_idx, o_probs, o_quants, o_loss);
}

// Round 6
// 198.744 us; speedup vs baseline: 1.5257x; 1.0529x over previous
//
#include <hip/hip_runtime.h>
#include <math.h>

// x[32,4096,32] f32, codebook[256,32] f32
// outputs (concat f32): o_idx[N], o_probs[N*256], o_quants[N*32], o_loss[N]
//
// Structure (r6 = r5 fixed): transposed, wave-autonomous. Each lane owns 4
// codes (codebook in VGPRs: cr[4][32] = 128 regs); one wave = all K=256.
// Each wave independently processes 32 rows: x broadcast via v_readlane
// (VALU pipe, compile-time lane indices) from a coalesced float4 stage.
// All reductions in-wave via compiler-managed update_dpp (template-constant
// ctrl -> satisfies the builtin's ICE requirement; hazard nops handled by
// the compiler). No __shared__, no barriers. Probs stores: lane l -> codes
// 4l..4l+3, one coalesced dwordx4 per row per lane (nontemporal).
constexpr int D   = 32;
constexpr int K   = 256;
constexpr int RPW = 32;          // rows per wave
constexpr int WPB = 4;           // waves per block (256 threads)
constexpr int RPB = RPW * WPB;   // 128 rows per block

typedef __attribute__((ext_vector_type(4))) float fvec4;

template <int CTRL, int RM, int BM>
__device__ __forceinline__ int dpp_i(int id, int v) {
    return __builtin_amdgcn_update_dpp(id, v, CTRL, RM, BM, false);
}

// ---- full-wave (64-lane) reductions, result valid in lane 63 ----
// Canonical LLVM AtomicOptimizer sequence: row_shr 1/2/4/8, then
// row_bcast15 (row_mask 0xA) and row_bcast31 (row_mask 0xC).
__device__ __forceinline__ float wred_max_f32(float v) {
    const int ID = 0xFF800000;   // -inf
    v = fmaxf(v, __int_as_float(dpp_i<0x111, 0xF, 0xF>(ID, __float_as_int(v))));
    v = fmaxf(v, __int_as_float(dpp_i<0x112, 0xF, 0xF>(ID, __float_as_int(v))));
    v = fmaxf(v, __int_as_float(dpp_i<0x114, 0xF, 0xF>(ID, __float_as_int(v))));
    v = fmaxf(v, __int_as_float(dpp_i<0x118, 0xF, 0xF>(ID, __float_as_int(v))));
    v = fmaxf(v, __int_as_float(dpp_i<0x142, 0xA, 0xF>(ID, __float_as_int(v))));
    v = fmaxf(v, __int_as_float(dpp_i<0x143, 0xC, 0xF>(ID, __float_as_int(v))));
    return v;
}
__device__ __forceinline__ float wred_add_f32(float v) {
    v = v + __int_as_float(dpp_i<0x111, 0xF, 0xF>(0, __float_as_int(v)));
    v = v + __int_as_float(dpp_i<0x112, 0xF, 0xF>(0, __float_as_int(v)));
    v = v + __int_as_float(dpp_i<0x114, 0xF, 0xF>(0, __float_as_int(v)));
    v = v + __int_as_float(dpp_i<0x118, 0xF, 0xF>(0, __float_as_int(v)));
    v = v + __int_as_float(dpp_i<0x142, 0xA, 0xF>(0, __float_as_int(v)));
    v = v + __int_as_float(dpp_i<0x143, 0xC, 0xF>(0, __float_as_int(v)));
    return v;
}
__device__ __forceinline__ unsigned wred_min_u32(unsigned v) {
    const int ID = (int)0xFFFFFFFF;
    unsigned f;
    f = (unsigned)dpp_i<0x111, 0xF, 0xF>(ID, (int)v); v = v < f ? v : f;
    f = (unsigned)dpp_i<0x112, 0xF, 0xF>(ID, (int)v); v = v < f ? v : f;
    f = (unsigned)dpp_i<0x114, 0xF, 0xF>(ID, (int)v); v = v < f ? v : f;
    f = (unsigned)dpp_i<0x118, 0xF, 0xF>(ID, (int)v); v = v < f ? v : f;
    f = (unsigned)dpp_i<0x142, 0xA, 0xF>(ID, (int)v); v = v < f ? v : f;
    f = (unsigned)dpp_i<0x143, 0xC, 0xF>(ID, (int)v); v = v < f ? v : f;
    return v;
}
__device__ __forceinline__ float bcast63_f32(float v) {
    return __int_as_float(__builtin_amdgcn_readlane(__float_as_int(v), 63));
}

__global__ __launch_bounds__(256, 2) void vq_kernel(
    const float* __restrict__ x,
    const float* __restrict__ cb,
    float* __restrict__ o_idx,
    float* __restrict__ o_probs,
    float* __restrict__ o_quants,
    float* __restrict__ o_loss)
{
    const int tid = threadIdx.x;
    const int l   = tid & 63;
    const int wu  = __builtin_amdgcn_readfirstlane(tid >> 6);   // uniform wave id
    const int wbase = blockIdx.x * RPB + wu * RPW;              // uniform row base

    // --- codebook: lane l owns codes 4l..4l+3, resident in VGPRs ---
    float cr[4][D];
    #pragma unroll
    for (int j = 0; j < 4; ++j) {
        const float4* cp = reinterpret_cast<const float4*>(cb) + (size_t)(l * 4 + j) * (D / 4);
        #pragma unroll
        for (int i = 0; i < D / 4; ++i) {
            float4 v = cp[i];
            cr[j][4 * i + 0] = v.x; cr[j][4 * i + 1] = v.y;
            cr[j][4 * i + 2] = v.z; cr[j][4 * i + 3] = v.w;
        }
    }
    float ncn[4];   // -||c||^2
    #pragma unroll
    for (int j = 0; j < 4; ++j) {
        float a0 = 0.f, a1 = 0.f, a2 = 0.f, a3 = 0.f;
        #pragma unroll
        for (int d = 0; d < D; d += 4) {
            a0 += cr[j][d]     * cr[j][d];     a1 += cr[j][d + 1] * cr[j][d + 1];
            a2 += cr[j][d + 2] * cr[j][d + 2]; a3 += cr[j][d + 3] * cr[j][d + 3];
        }
        ncn[j] = -((a0 + a1) + (a2 + a3));
    }

    // --- per-row ||x||^2 (loss only): lane l covers row l>>1, half l&1;
    //     pair-combine via quad_perm [1,0,3,2] ---
    float xnh;
    {
        const float4* xp = reinterpret_cast<const float4*>(x)
                         + (size_t)(wbase + (l >> 1)) * (D / 4) + (l & 1) * 4;
        float a = 0.f;
        #pragma unroll
        for (int i = 0; i < 4; ++i) {
            float4 v = xp[i];
            a += v.x * v.x + v.y * v.y + v.z * v.z + v.w * v.w;
        }
        float b = __int_as_float(dpp_i<0xB1, 0xF, 0xF>(0, __float_as_int(a)));
        xnh = a + b;   // both lanes of the pair hold the row norm
    }

    // parked per-row results (filled across the 32-row loop)
    float    lossv = 0.f, fidx = 0.f;
    unsigned gpark = 0;
    const unsigned codebase = (unsigned)(l * 4);

    for (int g = 0; g < RPW / 8; ++g) {
        // stage 8 rows of x: 1KB coalesced; lane l holds floats 4l..4l+3
        float4 vx = reinterpret_cast<const float4*>(x)[(size_t)(wbase + g * 8) * (D / 4) + l];

        #pragma unroll
        for (int rr = 0; rr < 8; ++rr) {
            const int r32 = g * 8 + rr;   // row within this wave's chunk

            // --- dots: x element broadcast via readlane (compile-time lane) ---
            float a0 = 0.f, a1 = 0.f, a2 = 0.f, a3 = 0.f;
            #pragma unroll
            for (int d = 0; d < D; ++d) {
                const int lane = rr * 8 + (d >> 2);
                const int c = d & 3;
                int sb = (c == 0) ? __float_as_int(vx.x)
                       : (c == 1) ? __float_as_int(vx.y)
                       : (c == 2) ? __float_as_int(vx.z)
                       :            __float_as_int(vx.w);
                float xs = __int_as_float(__builtin_amdgcn_readlane(sb, lane));
                a0 = fmaf(cr[0][d], xs, a0);
                a1 = fmaf(cr[1][d], xs, a1);
                a2 = fmaf(cr[2][d], xs, a2);
                a3 = fmaf(cr[3][d], xs, a3);
            }
            // logits (shifted by +xn, constant per row: cancels in softmax/argmax)
            float lg0 = fmaf(a0, 2.0f, ncn[0]);
            float lg1 = fmaf(a1, 2.0f, ncn[1]);
            float lg2 = fmaf(a2, 2.0f, ncn[2]);
            float lg3 = fmaf(a3, 2.0f, ncn[3]);

            // --- row max over all 256 codes (in-wave) ---
            float m = fmaxf(fmaxf(lg0, lg1), fmaxf(lg2, lg3));
            float gm = bcast63_f32(wred_max_f32(m));

            // --- argmax: min code index among bitwise-max matches ---
            unsigned c0 = (lg0 == gm) ? (codebase + 0) : 0xFFFFFFFFu;
            unsigned c1 = (lg1 == gm) ? (codebase + 1) : 0xFFFFFFFFu;
            unsigned c2 = (lg2 == gm) ? (codebase + 2) : 0xFFFFFFFFu;
            unsigned c3 = (lg3 == gm) ? (codebase + 3) : 0xFFFFFFFFu;
            unsigned cm = min(min(c0, c1), min(c2, c3));
            unsigned gi = (unsigned)__builtin_amdgcn_readlane((int)wred_min_u32(cm), 63) & 255u;

            // --- exp + sum ---
            float e0 = __expf(lg0 - gm), e1 = __expf(lg1 - gm);
            float e2 = __expf(lg2 - gm), e3 = __expf(lg3 - gm);
            float es = (e0 + e1) + (e2 + e3);
            float ws = wred_add_f32(es);
            float rs = bcast63_f32(__builtin_amdgcn_rcpf(ws));

            // --- probs: coalesced dwordx4 per lane (nontemporal stream) ---
            fvec4 p4 = { e0 * rs, e1 * rs, e2 * rs, e3 * rs };
            fvec4* pp = reinterpret_cast<fvec4*>(o_probs + (size_t)(wbase + r32) * K) + l;
            __builtin_nontemporal_store(p4, pp);

            // --- park gi / loss / idx for the epilogue ---
            bool mA = ((l >> 1) == r32);          // lanes 2r, 2r+1
            float lv = (xnh - gm) * 0.0390625f;   // 1.25 * d2min / 32
            lossv = mA ? lv : lossv;
            fidx  = mA ? (float)gi : fidx;
            gpark = ((unsigned)l == (unsigned)r32) ? gi : gpark;
        }
    }

    // --- epilogue: idx & loss (even lane -> loss, odd -> idx; row = l>>1) ---
    {
        const int r = l >> 1;
        if ((l & 1) == 0) o_loss[wbase + r] = lossv;
        else              o_idx [wbase + r] = fidx;
    }
    // --- quants: gi for row l>>1 pulled from lane l>>1; copy cb row (L1-hot).
    //     Lane pair covers one row: halves (l&1). Stores fully coalesced. ---
    {
        int gsel = __builtin_amdgcn_ds_bpermute((l >> 1) * 4, (int)gpark);
        unsigned gq = (unsigned)gsel & 255u;   // clamp: never OOB
        const float4* qs = reinterpret_cast<const float4*>(cb) + (size_t)gq * (D / 4) + (l & 1) * 4;
        float* qd = o_quants + (size_t)(wbase + (l >> 1)) * D + (l & 1) * 16;
        #pragma unroll
        for (int i = 0; i < 4; ++i) {
            float4 v = qs[i];
            fvec4 vv = { v.x, v.y, v.z, v.w };
            __builtin_nontemporal_store(vv, reinterpret_cast<fvec4*>(qd) + i);
        }
    }
}

extern "C" void kernel_launch(void* const* d_in, const int* in_sizes, int n_in,
                              void* d_out, int out_size, void* d_ws, size_t ws_size,
                              hipStream_t stream) {
    const float* x  = (const float*)d_in[0];
    const float* cb = (const float*)d_in[1];
    const int N = in_sizes[0] / D;   // 131072

    float* out      = (float*)d_out;
    float* o_idx    = out;
    float* o_probs  = o_idx + N;
    float* o_quants = o_probs + (size_t)N * K;
    float* o_loss   = o_quants + (size_t)N * D;

    const int grid = N / RPB;   // 1024 blocks of 256 threads
    vq_kernel<<<grid, 256, 0, stream>>>(x, cb, o_idx, o_probs, o_quants, o_loss);
}

// Round 7
// 194.124 us; speedup vs baseline: 1.5620x; 1.0238x over previous
//
#include <hip/hip_runtime.h>
#include <math.h>

// x[32,4096,32] f32, codebook[256,32] f32
// outputs (concat f32): o_idx[N], o_probs[N*256], o_quants[N*32], o_loss[N]
//
// Structure (r7): transposed, wave-autonomous (as r6: lane owns 4 codes,
// codebook in VGPRs, one wave = all K=256, wave processes 32 rows, all
// reductions in-wave via update_dpp). CHANGE vs r6: x is broadcast via
// wave-uniform LDS reads (8x ds_read_b128 per row, ~12cyc each on the LDS
// pipe, prefetchable) instead of 32x v_readlane per row on the VALU pipe
// (serial SGPR-write hazards). Block stages its 128 rows of x (16 KB) once.
// Logits pre-scaled by log2(e) -> exp is a bare v_exp_f32.
constexpr int D   = 32;
constexpr int K   = 256;
constexpr int RPW = 32;          // rows per wave
constexpr int WPB = 4;           // waves per block (256 threads)
constexpr int RPB = RPW * WPB;   // 128 rows per block

typedef __attribute__((ext_vector_type(4))) float fvec4;

template <int CTRL, int RM, int BM>
__device__ __forceinline__ int dpp_i(int id, int v) {
    return __builtin_amdgcn_update_dpp(id, v, CTRL, RM, BM, false);
}

// ---- full-wave (64-lane) reductions, result valid in lane 63 ----
__device__ __forceinline__ float wred_max_f32(float v) {
    const int ID = 0xFF800000;   // -inf
    v = fmaxf(v, __int_as_float(dpp_i<0x111, 0xF, 0xF>(ID, __float_as_int(v))));
    v = fmaxf(v, __int_as_float(dpp_i<0x112, 0xF, 0xF>(ID, __float_as_int(v))));
    v = fmaxf(v, __int_as_float(dpp_i<0x114, 0xF, 0xF>(ID, __float_as_int(v))));
    v = fmaxf(v, __int_as_float(dpp_i<0x118, 0xF, 0xF>(ID, __float_as_int(v))));
    v = fmaxf(v, __int_as_float(dpp_i<0x142, 0xA, 0xF>(ID, __float_as_int(v))));
    v = fmaxf(v, __int_as_float(dpp_i<0x143, 0xC, 0xF>(ID, __float_as_int(v))));
    return v;
}
__device__ __forceinline__ float wred_add_f32(float v) {
    v = v + __int_as_float(dpp_i<0x111, 0xF, 0xF>(0, __float_as_int(v)));
    v = v + __int_as_float(dpp_i<0x112, 0xF, 0xF>(0, __float_as_int(v)));
    v = v + __int_as_float(dpp_i<0x114, 0xF, 0xF>(0, __float_as_int(v)));
    v = v + __int_as_float(dpp_i<0x118, 0xF, 0xF>(0, __float_as_int(v)));
    v = v + __int_as_float(dpp_i<0x142, 0xA, 0xF>(0, __float_as_int(v)));
    v = v + __int_as_float(dpp_i<0x143, 0xC, 0xF>(0, __float_as_int(v)));
    return v;
}
__device__ __forceinline__ unsigned wred_min_u32(unsigned v) {
    const int ID = (int)0xFFFFFFFF;
    unsigned f;
    f = (unsigned)dpp_i<0x111, 0xF, 0xF>(ID, (int)v); v = v < f ? v : f;
    f = (unsigned)dpp_i<0x112, 0xF, 0xF>(ID, (int)v); v = v < f ? v : f;
    f = (unsigned)dpp_i<0x114, 0xF, 0xF>(ID, (int)v); v = v < f ? v : f;
    f = (unsigned)dpp_i<0x118, 0xF, 0xF>(ID, (int)v); v = v < f ? v : f;
    f = (unsigned)dpp_i<0x142, 0xA, 0xF>(ID, (int)v); v = v < f ? v : f;
    f = (unsigned)dpp_i<0x143, 0xC, 0xF>(ID, (int)v); v = v < f ? v : f;
    return v;
}
__device__ __forceinline__ float bcast63_f32(float v) {
    return __int_as_float(__builtin_amdgcn_readlane(__float_as_int(v), 63));
}

__global__ __launch_bounds__(256, 3) void vq_kernel(
    const float* __restrict__ x,
    const float* __restrict__ cb,
    float* __restrict__ o_idx,
    float* __restrict__ o_probs,
    float* __restrict__ o_quants,
    float* __restrict__ o_loss)
{
    __shared__ float4 xlds[RPB * (D / 4)];   // 16 KB: block's 128 rows of x

    const int tid = threadIdx.x;
    const int l   = tid & 63;
    const int wu  = __builtin_amdgcn_readfirstlane(tid >> 6);   // uniform wave id
    const int wbase = blockIdx.x * RPB + wu * RPW;              // uniform row base

    // --- stage x block: 1024 float4 by 256 threads, coalesced ---
    {
        const float4* xg = reinterpret_cast<const float4*>(x)
                         + (size_t)blockIdx.x * RPB * (D / 4);
        #pragma unroll
        for (int i = 0; i < 4; ++i) xlds[tid + i * 256] = xg[tid + i * 256];
    }

    // --- codebook: lane l owns codes 4l..4l+3, resident in VGPRs ---
    constexpr float SC     = 1.4426950408889634f;   // log2(e)
    constexpr float TWO_SC = 2.8853900817779268f;   // 2*log2(e)
    float cr[4][D];
    #pragma unroll
    for (int j = 0; j < 4; ++j) {
        const float4* cp = reinterpret_cast<const float4*>(cb) + (size_t)(l * 4 + j) * (D / 4);
        #pragma unroll
        for (int i = 0; i < D / 4; ++i) {
            float4 v = cp[i];
            cr[j][4 * i + 0] = v.x; cr[j][4 * i + 1] = v.y;
            cr[j][4 * i + 2] = v.z; cr[j][4 * i + 3] = v.w;
        }
    }
    float ncn[4];   // -log2e * ||c||^2  (logits kept in scaled domain)
    #pragma unroll
    for (int j = 0; j < 4; ++j) {
        float a0 = 0.f, a1 = 0.f, a2 = 0.f, a3 = 0.f;
        #pragma unroll
        for (int d = 0; d < D; d += 4) {
            a0 += cr[j][d]     * cr[j][d];     a1 += cr[j][d + 1] * cr[j][d + 1];
            a2 += cr[j][d + 2] * cr[j][d + 2]; a3 += cr[j][d + 3] * cr[j][d + 3];
        }
        ncn[j] = -((a0 + a1) + (a2 + a3)) * SC;
    }

    // --- per-row ||x||^2 (loss only): lane l covers row l>>1, half l&1;
    //     pair-combine via quad_perm [1,0,3,2] (global read, L1/L2-hot) ---
    float xnh;
    {
        const float4* xp = reinterpret_cast<const float4*>(x)
                         + (size_t)(wbase + (l >> 1)) * (D / 4) + (l & 1) * 4;
        float a = 0.f;
        #pragma unroll
        for (int i = 0; i < 4; ++i) {
            float4 v = xp[i];
            a += v.x * v.x + v.y * v.y + v.z * v.z + v.w * v.w;
        }
        float b = __int_as_float(dpp_i<0xB1, 0xF, 0xF>(0, __float_as_int(a)));
        xnh = a + b;   // both lanes of the pair hold the row norm
    }

    __syncthreads();   // xlds ready; waves independent from here on

    // parked per-row results
    float    lossv = 0.f, fidx = 0.f;
    unsigned gpark = 0;
    const unsigned codebase = (unsigned)(l * 4);
    const float4* xw4 = xlds + wu * RPW * (D / 4);   // wave's 32-row slice

    for (int r = 0; r < RPW; ++r) {
        // --- dots: x broadcast via wave-uniform ds_read_b128 (8 per row) ---
        float a0 = 0.f, a1 = 0.f, a2 = 0.f, a3 = 0.f;
        #pragma unroll
        for (int q = 0; q < D / 4; ++q) {
            float4 xv = xw4[r * (D / 4) + q];
            #pragma unroll
            for (int c = 0; c < 4; ++c) {
                const int d = q * 4 + c;
                const float xs = (&xv.x)[c];
                a0 = fmaf(cr[0][d], xs, a0);
                a1 = fmaf(cr[1][d], xs, a1);
                a2 = fmaf(cr[2][d], xs, a2);
                a3 = fmaf(cr[3][d], xs, a3);
            }
        }
        // scaled logits: slg = log2e * (2*dot - ||c||^2)  (+log2e*xn, const/row)
        float slg0 = fmaf(a0, TWO_SC, ncn[0]);
        float slg1 = fmaf(a1, TWO_SC, ncn[1]);
        float slg2 = fmaf(a2, TWO_SC, ncn[2]);
        float slg3 = fmaf(a3, TWO_SC, ncn[3]);

        // --- row max over all 256 codes (in-wave) ---
        float m = fmaxf(fmaxf(slg0, slg1), fmaxf(slg2, slg3));
        float gm = bcast63_f32(wred_max_f32(m));

        // --- argmax: min code index among bitwise-max matches ---
        unsigned c0 = (slg0 == gm) ? (codebase + 0) : 0xFFFFFFFFu;
        unsigned c1 = (slg1 == gm) ? (codebase + 1) : 0xFFFFFFFFu;
        unsigned c2 = (slg2 == gm) ? (codebase + 2) : 0xFFFFFFFFu;
        unsigned c3 = (slg3 == gm) ? (codebase + 3) : 0xFFFFFFFFu;
        unsigned cm = min(min(c0, c1), min(c2, c3));
        unsigned gi = (unsigned)__builtin_amdgcn_readlane((int)wred_min_u32(cm), 63) & 255u;

        // --- exp (scaled domain: bare v_exp_f32) + sum ---
        float e0 = __builtin_amdgcn_exp2f(slg0 - gm);
        float e1 = __builtin_amdgcn_exp2f(slg1 - gm);
        float e2 = __builtin_amdgcn_exp2f(slg2 - gm);
        float e3 = __builtin_amdgcn_exp2f(slg3 - gm);
        float es = (e0 + e1) + (e2 + e3);
        float ws = wred_add_f32(es);
        float rs = bcast63_f32(__builtin_amdgcn_rcpf(ws));

        // --- probs: coalesced dwordx4 per lane (nontemporal stream) ---
        fvec4 p4 = { e0 * rs, e1 * rs, e2 * rs, e3 * rs };
        fvec4* pp = reinterpret_cast<fvec4*>(o_probs + (size_t)(wbase + r) * K) + l;
        __builtin_nontemporal_store(p4, pp);

        // --- park gi / loss / idx for the epilogue ---
        bool mA = ((l >> 1) == r);            // lanes 2r, 2r+1
        // loss = 1.25 * d2min / 32;  d2min = xn - gm/log2e = xn - gm*ln2
        float lv = (xnh - gm * 0.6931471805599453f) * 0.0390625f;
        lossv = mA ? lv : lossv;
        fidx  = mA ? (float)gi : fidx;
        gpark = ((unsigned)l == (unsigned)r) ? gi : gpark;
    }

    // --- epilogue: idx & loss (even lane -> loss, odd -> idx; row = l>>1) ---
    {
        const int r = l >> 1;
        if ((l & 1) == 0) o_loss[wbase + r] = lossv;
        else              o_idx [wbase + r] = fidx;
    }
    // --- quants: gi for row l>>1 pulled from lane l>>1; copy cb row (L1-hot).
    //     Lane pair covers one row: halves (l&1). Stores fully coalesced. ---
    {
        int gsel = __builtin_amdgcn_ds_bpermute((l >> 1) * 4, (int)gpark);
        unsigned gq = (unsigned)gsel & 255u;   // clamp: never OOB
        const float4* qs = reinterpret_cast<const float4*>(cb) + (size_t)gq * (D / 4) + (l & 1) * 4;
        float* qd = o_quants + (size_t)(wbase + (l >> 1)) * D + (l & 1) * 16;
        #pragma unroll
        for (int i = 0; i < 4; ++i) {
            float4 v = qs[i];
            fvec4 vv = { v.x, v.y, v.z, v.w };
            __builtin_nontemporal_store(vv, reinterpret_cast<fvec4*>(qd) + i);
        }
    }
}

extern "C" void kernel_launch(void* const* d_in, const int* in_sizes, int n_in,
                              void* d_out, int out_size, void* d_ws, size_t ws_size,
                              hipStream_t stream) {
    const float* x  = (const float*)d_in[0];
    const float* cb = (const float*)d_in[1];
    const int N = in_sizes[0] / D;   // 131072

    float* out      = (float*)d_out;
    float* o_idx    = out;
    float* o_probs  = o_idx + N;
    float* o_quants = o_probs + (size_t)N * K;
    float* o_loss   = o_quants + (size_t)N * D;

    const int grid = N / RPB;   // 1024 blocks of 256 threads
    vq_kernel<<<grid, 256, 0, stream>>>(x, cb, o_idx, o_probs, o_quants, o_loss);
}